// Round 1
// baseline (55.314 us; speedup 1.0000x reference)
//
#include <hip/hip_runtime.h>

// Analytic collapse of the quantum conv:
//   out[b,f,h,w] = sum_c  prod_{k=1..8} cos( x_patch[b,c,h,w,k] + weights[0,k] )
// where x_patch[k] = x[b,c,h+k/3-1, w+k%3-1] (zero outside bounds), k=0 (top-left)
// drops out because Z0 conjugated through the CNOT ring becomes Z1..Z8.

#define Bn 8
#define Cn 4
#define Hn 32
#define Wn 32
#define Fn 8
#define NPIX (Bn * Hn * Wn)   // 8192

__global__ __launch_bounds__(256) void qconv_kernel(
    const float* __restrict__ x,      // (B, C, H, W)
    const float* __restrict__ wts,    // (1, 9)
    float* __restrict__ out)          // (B, F, H, W)
{
    int idx = blockIdx.x * blockDim.x + threadIdx.x;
    if (idx >= NPIX) return;

    int wcol = idx & (Wn - 1);
    int hrow = (idx >> 5) & (Hn - 1);
    int b    = idx >> 10;

    // weights (uniform across threads -> scalar loads)
    float wt[9];
#pragma unroll
    for (int i = 0; i < 9; ++i) wt[i] = wts[i];

    float sum = 0.0f;
#pragma unroll
    for (int c = 0; c < Cn; ++c) {
        const float* xc = x + ((b * Cn + c) * Hn) * Wn;
        float prod = 1.0f;
#pragma unroll
        for (int k = 1; k < 9; ++k) {
            int p  = k / 3;
            int q  = k % 3;
            int hh = hrow + p - 1;
            int ww = wcol + q - 1;
            float v = 0.0f;
            if (hh >= 0 && hh < Hn && ww >= 0 && ww < Wn)
                v = xc[hh * Wn + ww];
            prod *= __cosf(v + wt[k]);
        }
        sum += prod;
    }

    // broadcast over the 8 output filters
    float* ob = out + (b * Fn * Hn + hrow) * Wn + wcol;
#pragma unroll
    for (int f = 0; f < Fn; ++f)
        ob[f * Hn * Wn] = sum;
}

extern "C" void kernel_launch(void* const* d_in, const int* in_sizes, int n_in,
                              void* d_out, int out_size, void* d_ws, size_t ws_size,
                              hipStream_t stream) {
    const float* x   = (const float*)d_in[0];   // 8*4*32*32 = 32768
    const float* wts = (const float*)d_in[1];   // 1*9 = 9
    float* out       = (float*)d_out;           // 8*8*32*32 = 65536

    qconv_kernel<<<NPIX / 256, 256, 0, stream>>>(x, wts, out);
}